// Round 18
// baseline (139.536 us; speedup 1.0000x reference)
//
#include <hip/hip_runtime.h>
#include <math.h>

#define D 100
#define NEG_SLOPE 0.2f
#define CHUNK 16
#define ROWU 52          // uints per packed-f16 row, padded 50->52 for 16B align
#define NBLOCKS 2048     // 8 blocks/CU x 256 CU — fully co-resident (grid-stride)

// compiler-only memory barrier (validated R17: same-wave LDS is pipe-ordered,
// no lgkmcnt(0) drain needed; this only stops compiler reordering)
#define COMPILER_FENCE() asm volatile("" ::: "memory")

typedef _Float16 f16x2 __attribute__((ext_vector_type(2)));
union U32H2 { unsigned int u; f16x2 h; };

__device__ __forceinline__ unsigned int pkh2(float x, float y) {
    U32H2 c; c.h.x = (_Float16)x; c.h.y = (_Float16)y; return c.u;
}

// 2-wide f16 dot + fp32 accumulate: v_dot2_f32_f16
__device__ __forceinline__ float dot2u(unsigned int au, unsigned int xu, float acc) {
#if __has_builtin(__builtin_amdgcn_fdot2)
    U32H2 a, x; a.u = au; x.u = xu;
    return __builtin_amdgcn_fdot2(a.h, x.h, acc, false);
#else
    U32H2 a, x; a.u = au; x.u = xu;
    return acc + (float)a.h.x * (float)x.h.x + (float)a.h.y * (float)x.h.y;
#endif
}

// DPP cross-lane (VALU pipe).
template<int CTRL>
__device__ __forceinline__ float dppf(float x) {
    return __uint_as_float((unsigned)__builtin_amdgcn_update_dpp(
        0, (int)__float_as_uint(x), CTRL, 0xF, 0xF, true));
}
__device__ __forceinline__ float red16_max(float x) {
    x = fmaxf(x, dppf<0xB1>(x));    // quad_perm xor1
    x = fmaxf(x, dppf<0x4E>(x));    // quad_perm xor2
    x = fmaxf(x, dppf<0x124>(x));   // row_ror:4
    x = fmaxf(x, dppf<0x128>(x));   // row_ror:8
    return x;
}
__device__ __forceinline__ float red16_sum(float x) {
    x += dppf<0xB1>(x);
    x += dppf<0x4E>(x);
    x += dppf<0x124>(x);
    x += dppf<0x128>(x);
    return x;
}

// Fused prep: t < P: row_ptr boundary scatter; t < total25: fp32 -> f16 pack.
__global__ void prep_kernel(const int* __restrict__ seg,
                            int* __restrict__ row_ptr,
                            const float* __restrict__ hidden,
                            unsigned int* __restrict__ hb,
                            int n, int P, int total25)
{
    int t = blockIdx.x * blockDim.x + threadIdx.x;
    if (t < P) {
        int s0 = seg[t];
        if (t == 0)
            for (int v = 0; v <= s0; v++) row_ptr[v] = 0;
        int s1 = (t + 1 < P) ? seg[t + 1] : n;
        for (int v = s0 + 1; v <= s1; v++) row_ptr[v] = t + 1;
    }
    if (t < total25) {
        int node = t / 25, k = t - node * 25;   // 25 float4-groups per row
        float4 f = ((const float4*)hidden)[t];
        *(uint2*)&hb[node * ROWU + 2 * k] =
            make_uint2(pkh2(f.x, f.y), pkh2(f.z, f.w));
    }
}

// Persistent grid-stride, one wave per node per iteration. CHUNK=16,
// 4 lanes/pair, f16 gathers + fdot2, DPP softmax, compiler-only fences,
// coalesced nbr preload. R18: (1) 2048 co-resident blocks — steady 32
// waves/CU instead of 12.5K draining blocks (achieved occ was pinned ~67%);
// (2) phase B in fmaf((float)f16,f32,f32) form -> v_fma_mix_f32 (1 op vs
// cvt+fma), halving the biggest VALU block.
__launch_bounds__(256, 8)
__global__ void gat_agg_kernel(const float* __restrict__ hidden,
                               const float* __restrict__ W,
                               const int* __restrict__ nbr,
                               const int* __restrict__ row_ptr,
                               const unsigned int* __restrict__ hb,
                               float* __restrict__ out,
                               int n, int P)
{
    __shared__ __align__(16) unsigned int s_hwp[4][ROWU];         // 0.83 KB
    __shared__ __align__(16) unsigned int s_rows[4][CHUNK][ROWU]; // 13.3 KB
    __shared__ __align__(16) float        s_e[4][CHUNK];          // 0.25 KB

    const int lane = threadIdx.x & 63;
    const int wid  = threadIdx.x >> 6;

    const int q  = lane >> 4;    // quarter 0..3: uint4s q*3..q*3+2 (+tail on q0)
    const int jl = lane & 15;    // pair slot within the 16-chunk
    const int t0 = q * 3;

    const int vstride = NBLOCKS * 4;

    for (int v = blockIdx.x * 4 + wid; v < n; v += vstride) {

        // hw[d] = hidden[v][d] * W[d] (fp32 product, f16-packed into LDS)
        if (lane < 50) {
            float2 h2 = ((const float2*)(hidden + (long)v * D))[lane];
            float2 w2 = ((const float2*)W)[lane];
            s_hwp[wid][lane] = pkh2(h2.x * w2.x, h2.y * w2.y);
        }
        COMPILER_FENCE();

        const int start = row_ptr[v];
        const int end   = row_ptr[v + 1];

        if (end <= start) {      // empty segment: zeros (matches reference)
            if (lane < D / 2)
                ((float2*)(out + (long)v * D))[lane] = make_float2(0.f, 0.f);
            continue;
        }

        // one coalesced read covers the first 64 pairs (deg <= 64 ~ always)
        const int preN = nbr[min(start + lane, P - 1)];

        // hw fragment in registers (loop-invariant per node; 14 regs)
        const uint4* hwq = ((const uint4*)&s_hwp[wid][0]) + t0;
        const uint4 a0 = hwq[0], a1 = hwq[1], a2 = hwq[2];
        uint2 at = make_uint2(0u, 0u);
        if (q == 0) at = *(const uint2*)&s_hwp[wid][48];

        float m = -INFINITY, z = 0.f;
        float accx = 0.f, accy = 0.f;

        for (int c = start; c < end; c += CHUNK) {
            const int  cnt = min(CHUNK, end - c);
            const bool pv  = jl < cnt;
            const int  off = c - start;

            // neighbor index: shfl from preload (chunks 0..3), else global.
            int nbv;
            if (off + CHUNK <= 64) {             // wave-uniform branch
                nbv = __shfl(preN, off + jl, 64);
                nbv = pv ? nbv : 0;
            } else {
                nbv = pv ? nbr[c + jl] : 0;
            }
            const uint4* row16 = ((const uint4*)hb) + nbv * (ROWU / 4) + t0;

            // ---- Phase A: f16 quarter-row gather (3x16B + 8B tail), fdot2 --
            uint4 x0 = row16[0], x1 = row16[1], x2 = row16[2];
            uint2 xt = make_uint2(0u, 0u);
            if (q == 0) xt = *(const uint2*)&hb[nbv * ROWU + 48]; // dims 96..99

            float p0 = 0.f, p1 = 0.f, p2 = 0.f, p3 = 0.f;
            p0 = dot2u(a0.x, x0.x, p0);  p1 = dot2u(a0.y, x0.y, p1);
            p2 = dot2u(a0.z, x0.z, p2);  p3 = dot2u(a0.w, x0.w, p3);
            p0 = dot2u(a1.x, x1.x, p0);  p1 = dot2u(a1.y, x1.y, p1);
            p2 = dot2u(a1.z, x1.z, p2);  p3 = dot2u(a1.w, x1.w, p3);
            p0 = dot2u(a2.x, x2.x, p0);  p1 = dot2u(a2.y, x2.y, p1);
            p2 = dot2u(a2.z, x2.z, p2);  p3 = dot2u(a2.w, x2.w, p3);
            if (q == 0) {
                p0 = dot2u(at.x, xt.x, p0);
                p1 = dot2u(at.y, xt.y, p1);
            }

            // stage raw f16 row to LDS (16B-aligned: ROWU*4 = 208 = 13*16)
            uint4* dst16 = ((uint4*)&s_rows[wid][jl][0]) + t0;
            dst16[0] = x0; dst16[1] = x1; dst16[2] = x2;
            if (q == 0) *(uint2*)&s_rows[wid][jl][48] = xt;

            float part = (p0 + p1) + (p2 + p3);
            part += __shfl_xor(part, 16, 64);    // combine quarters (LDS pipe)
            part += __shfl_xor(part, 32, 64);
            const float s = pv ? (part >= 0.f ? part : NEG_SLOPE * part)
                               : -INFINITY;

            // ---- online softmax: DPP trees within each 16-group ----
            const float m_new = fmaxf(m, red16_max(s));
            const float scale = __expf(m - m_new);       // first chunk: 0
            const float e     = pv ? __expf(s - m_new) : 0.f;
            z = z * scale + red16_sum(e);
            accx *= scale; accy *= scale;

            if (lane < CHUNK) s_e[wid][lane] = e;        // q0 lanes: jl == lane
            COMPILER_FENCE();    // order stores before phase-B reads (same wave)

            // ---- Phase B: lane-per-dim accumulate; fma_mix form ----
            const int cnt4 = (cnt + 3) & ~3;             // <= 16
            if (lane < D / 2) {
                for (int j0 = 0; j0 < cnt4; j0 += 4) {
                    const float4 ev = *(const float4*)&s_e[wid][j0]; // broadcast
                    U32H2 u0, u1, u2, u3;
                    u0.u = s_rows[wid][j0    ][lane];
                    u1.u = s_rows[wid][j0 + 1][lane];
                    u2.u = s_rows[wid][j0 + 2][lane];
                    u3.u = s_rows[wid][j0 + 3][lane];
                    accx = fmaf((float)u0.h.x, ev.x, accx);
                    accy = fmaf((float)u0.h.y, ev.x, accy);
                    accx = fmaf((float)u1.h.x, ev.y, accx);
                    accy = fmaf((float)u1.h.y, ev.y, accy);
                    accx = fmaf((float)u2.h.x, ev.z, accx);
                    accy = fmaf((float)u2.h.y, ev.z, accy);
                    accx = fmaf((float)u3.h.x, ev.w, accx);
                    accy = fmaf((float)u3.h.y, ev.w, accy);
                }
            }
            COMPILER_FENCE();    // phase-B reads before next chunk's stores
            m = m_new;
        }

        if (lane < D / 2) {
            const float inv = 1.f / z;
            ((float2*)(out + (long)v * D))[lane] =
                make_float2(accx * inv, accy * inv);
        }
    }
}

extern "C" void kernel_launch(void* const* d_in, const int* in_sizes, int n_in,
                              void* d_out, int out_size, void* d_ws, size_t ws_size,
                              hipStream_t stream) {
    const float* hidden = (const float*)d_in[0];
    const float* W      = (const float*)d_in[1];
    const int*   seg    = (const int*)d_in[2];
    const int*   nbr    = (const int*)d_in[3];
    float*       out    = (float*)d_out;

    const int Ddim = in_sizes[1];           // 100
    const int n    = in_sizes[0] / Ddim;    // 50000
    const int P    = in_sizes[2];           // ~1.3M pairs

    // ws layout: row_ptr (n+1 ints) | hb (n*ROWU uints, 256B-aligned)
    int* row_ptr = (int*)d_ws;
    size_t hb_off = (((size_t)(n + 1) * 4) + 255) & ~(size_t)255;
    unsigned int* hb = (unsigned int*)((char*)d_ws + hb_off);

    const int total25 = n * 25;             // float4-groups in hidden
    const int tmax    = (P > total25) ? P : total25;
    hipLaunchKernelGGL(prep_kernel, dim3((tmax + 255) / 256), dim3(256), 0, stream,
                       seg, row_ptr, hidden, hb, n, P, total25);
    hipLaunchKernelGGL(gat_agg_kernel, dim3(NBLOCKS), dim3(256), 0, stream,
                       hidden, W, nbr, row_ptr, hb, out, n, P);
}

// Round 19
// 126.957 us; speedup vs baseline: 1.0991x; 1.0991x over previous
//
#include <hip/hip_runtime.h>
#include <math.h>

#define D 100
#define NEG_SLOPE 0.2f
#define CHUNK 16
#define ROWU 52          // uints per packed-f16 row, padded 50->52 for 16B align

// compiler-only memory barrier (validated R17: same-wave LDS is pipe-ordered,
// no lgkmcnt(0) drain needed; this only stops compiler reordering)
#define COMPILER_FENCE() asm volatile("" ::: "memory")

typedef _Float16 f16x2 __attribute__((ext_vector_type(2)));
union U32H2 { unsigned int u; f16x2 h; };

__device__ __forceinline__ unsigned int pkh2(float x, float y) {
    U32H2 c; c.h.x = (_Float16)x; c.h.y = (_Float16)y; return c.u;
}

// 2-wide f16 dot + fp32 accumulate: v_dot2_f32_f16
__device__ __forceinline__ float dot2u(unsigned int au, unsigned int xu, float acc) {
#if __has_builtin(__builtin_amdgcn_fdot2)
    U32H2 a, x; a.u = au; x.u = xu;
    return __builtin_amdgcn_fdot2(a.h, x.h, acc, false);
#else
    U32H2 a, x; a.u = au; x.u = xu;
    return acc + (float)a.h.x * (float)x.h.x + (float)a.h.y * (float)x.h.y;
#endif
}

// DPP cross-lane (VALU pipe).
template<int CTRL>
__device__ __forceinline__ float dppf(float x) {
    return __uint_as_float((unsigned)__builtin_amdgcn_update_dpp(
        0, (int)__float_as_uint(x), CTRL, 0xF, 0xF, true));
}
__device__ __forceinline__ float red16_max(float x) {
    x = fmaxf(x, dppf<0xB1>(x));    // quad_perm xor1
    x = fmaxf(x, dppf<0x4E>(x));    // quad_perm xor2
    x = fmaxf(x, dppf<0x124>(x));   // row_ror:4
    x = fmaxf(x, dppf<0x128>(x));   // row_ror:8
    return x;
}
__device__ __forceinline__ float red16_sum(float x) {
    x += dppf<0xB1>(x);
    x += dppf<0x4E>(x);
    x += dppf<0x124>(x);
    x += dppf<0x128>(x);
    return x;
}

// Fused prep: t < P: row_ptr boundary scatter; t < total25: fp32 -> f16 pack.
__global__ void prep_kernel(const int* __restrict__ seg,
                            int* __restrict__ row_ptr,
                            const float* __restrict__ hidden,
                            unsigned int* __restrict__ hb,
                            int n, int P, int total25)
{
    int t = blockIdx.x * blockDim.x + threadIdx.x;
    if (t < P) {
        int s0 = seg[t];
        if (t == 0)
            for (int v = 0; v <= s0; v++) row_ptr[v] = 0;
        int s1 = (t + 1 < P) ? seg[t + 1] : n;
        for (int v = s0 + 1; v <= s1; v++) row_ptr[v] = t + 1;
    }
    if (t < total25) {
        int node = t / 25, k = t - node * 25;   // 25 float4-groups per row
        float4 f = ((const float4*)hidden)[t];
        *(uint2*)&hb[node * ROWU + 2 * k] =
            make_uint2(pkh2(f.x, f.y), pkh2(f.z, f.w));
    }
}

// One wave per node, one node per wave (12.5K blocks — the HW scheduler
// load-balances irregular degrees better than persistent grid-stride: R18
// regressed 47->59 us with worse L2 locality). CHUNK=16, 4 lanes/pair, f16
// gathers + fdot2, DPP softmax, compiler-only fences, coalesced nbr preload,
// phase B via fmaf((float)f16,f32,f32) -> v_fma_mix_f32.
__launch_bounds__(256, 8)
__global__ void gat_agg_kernel(const float* __restrict__ hidden,
                               const float* __restrict__ W,
                               const int* __restrict__ nbr,
                               const int* __restrict__ row_ptr,
                               const unsigned int* __restrict__ hb,
                               float* __restrict__ out,
                               int n, int P)
{
    __shared__ __align__(16) unsigned int s_hwp[4][ROWU];         // 0.83 KB
    __shared__ __align__(16) unsigned int s_rows[4][CHUNK][ROWU]; // 13.3 KB
    __shared__ __align__(16) float        s_e[4][CHUNK];          // 0.25 KB

    const int lane = threadIdx.x & 63;
    const int wid  = threadIdx.x >> 6;
    const int v    = blockIdx.x * 4 + wid;
    if (v >= n) return;          // wave-uniform exit; no block barriers used

    // hw[d] = hidden[v][d] * W[d] (fp32 product, f16-packed into LDS)
    if (lane < 50) {
        float2 h2 = ((const float2*)(hidden + (long)v * D))[lane];
        float2 w2 = ((const float2*)W)[lane];
        s_hwp[wid][lane] = pkh2(h2.x * w2.x, h2.y * w2.y);
    }
    COMPILER_FENCE();

    const int start = row_ptr[v];
    const int end   = row_ptr[v + 1];

    if (end <= start) {          // empty segment: zeros (matches reference)
        if (lane < D / 2)
            ((float2*)(out + (long)v * D))[lane] = make_float2(0.f, 0.f);
        return;
    }

    // one coalesced read covers the first 64 pairs (deg <= 64 ~ always)
    const int preN = nbr[min(start + lane, P - 1)];

    const int q  = lane >> 4;    // quarter 0..3: uint4s q*3..q*3+2 (+tail on q0)
    const int jl = lane & 15;    // pair slot within the 16-chunk
    const int t0 = q * 3;

    // hoist hw fragment into registers (loop-invariant; 14 regs)
    const uint4* hwq = ((const uint4*)&s_hwp[wid][0]) + t0;
    const uint4 a0 = hwq[0], a1 = hwq[1], a2 = hwq[2];
    uint2 at = make_uint2(0u, 0u);
    if (q == 0) at = *(const uint2*)&s_hwp[wid][48];

    float m = -INFINITY, z = 0.f;
    float accx = 0.f, accy = 0.f;

    for (int c = start; c < end; c += CHUNK) {
        const int  cnt = min(CHUNK, end - c);
        const bool pv  = jl < cnt;
        const int  off = c - start;

        // neighbor index: shfl from the preload (chunks 0..3), else global.
        // invalid lanes use row 0 (finite, in-bounds); e=0 masks it later.
        int nbv;
        if (off + CHUNK <= 64) {             // wave-uniform branch
            nbv = __shfl(preN, off + jl, 64);
            nbv = pv ? nbv : 0;
        } else {
            nbv = pv ? nbr[c + jl] : 0;
        }
        const uint4* row16 = ((const uint4*)hb) + nbv * (ROWU / 4) + t0;

        // ---- Phase A: f16 quarter-row gather (3x16B + 8B tail), fdot2 ----
        uint4 x0 = row16[0], x1 = row16[1], x2 = row16[2];
        uint2 xt = make_uint2(0u, 0u);
        if (q == 0) xt = *(const uint2*)&hb[nbv * ROWU + 48];   // dims 96..99

        float p0 = 0.f, p1 = 0.f, p2 = 0.f, p3 = 0.f;
        p0 = dot2u(a0.x, x0.x, p0);  p1 = dot2u(a0.y, x0.y, p1);
        p2 = dot2u(a0.z, x0.z, p2);  p3 = dot2u(a0.w, x0.w, p3);
        p0 = dot2u(a1.x, x1.x, p0);  p1 = dot2u(a1.y, x1.y, p1);
        p2 = dot2u(a1.z, x1.z, p2);  p3 = dot2u(a1.w, x1.w, p3);
        p0 = dot2u(a2.x, x2.x, p0);  p1 = dot2u(a2.y, x2.y, p1);
        p2 = dot2u(a2.z, x2.z, p2);  p3 = dot2u(a2.w, x2.w, p3);
        if (q == 0) {
            p0 = dot2u(at.x, xt.x, p0);
            p1 = dot2u(at.y, xt.y, p1);
        }

        // stage raw f16 row to LDS (16B-aligned: ROWU*4 = 208 = 13*16)
        uint4* dst16 = ((uint4*)&s_rows[wid][jl][0]) + t0;
        dst16[0] = x0; dst16[1] = x1; dst16[2] = x2;
        if (q == 0) *(uint2*)&s_rows[wid][jl][48] = xt;

        float part = (p0 + p1) + (p2 + p3);
        part += __shfl_xor(part, 16, 64);    // combine quarters (LDS pipe)
        part += __shfl_xor(part, 32, 64);
        const float s = pv ? (part >= 0.f ? part : NEG_SLOPE * part)
                           : -INFINITY;

        // ---- online softmax: DPP trees within each 16-group ----
        const float m_new = fmaxf(m, red16_max(s));
        const float scale = __expf(m - m_new);         // first chunk: 0
        const float e     = pv ? __expf(s - m_new) : 0.f;
        z = z * scale + red16_sum(e);
        accx *= scale; accy *= scale;

        if (lane < CHUNK) s_e[wid][lane] = e;          // q0 lanes: jl == lane
        COMPILER_FENCE();        // order stores before phase-B reads (same wave)

        // ---- Phase B: lane-per-dim accumulate; v_fma_mix form ----
        const int cnt4 = (cnt + 3) & ~3;               // <= 16
        if (lane < D / 2) {
            for (int j0 = 0; j0 < cnt4; j0 += 4) {
                const float4 ev = *(const float4*)&s_e[wid][j0];  // broadcast
                U32H2 u0, u1, u2, u3;
                u0.u = s_rows[wid][j0    ][lane];
                u1.u = s_rows[wid][j0 + 1][lane];
                u2.u = s_rows[wid][j0 + 2][lane];
                u3.u = s_rows[wid][j0 + 3][lane];
                accx = fmaf((float)u0.h.x, ev.x, accx);
                accy = fmaf((float)u0.h.y, ev.x, accy);
                accx = fmaf((float)u1.h.x, ev.y, accx);
                accy = fmaf((float)u1.h.y, ev.y, accy);
                accx = fmaf((float)u2.h.x, ev.z, accx);
                accy = fmaf((float)u2.h.y, ev.z, accy);
                accx = fmaf((float)u3.h.x, ev.w, accx);
                accy = fmaf((float)u3.h.y, ev.w, accy);
            }
        }
        COMPILER_FENCE();        // phase-B reads before next chunk's stores
        m = m_new;
    }

    if (lane < D / 2) {
        const float inv = 1.f / z;
        ((float2*)(out + (long)v * D))[lane] = make_float2(accx * inv, accy * inv);
    }
}

extern "C" void kernel_launch(void* const* d_in, const int* in_sizes, int n_in,
                              void* d_out, int out_size, void* d_ws, size_t ws_size,
                              hipStream_t stream) {
    const float* hidden = (const float*)d_in[0];
    const float* W      = (const float*)d_in[1];
    const int*   seg    = (const int*)d_in[2];
    const int*   nbr    = (const int*)d_in[3];
    float*       out    = (float*)d_out;

    const int Ddim = in_sizes[1];           // 100
    const int n    = in_sizes[0] / Ddim;    // 50000
    const int P    = in_sizes[2];           // ~1.3M pairs

    // ws layout: row_ptr (n+1 ints) | hb (n*ROWU uints, 256B-aligned)
    int* row_ptr = (int*)d_ws;
    size_t hb_off = (((size_t)(n + 1) * 4) + 255) & ~(size_t)255;
    unsigned int* hb = (unsigned int*)((char*)d_ws + hb_off);

    const int total25 = n * 25;             // float4-groups in hidden
    const int tmax    = (P > total25) ? P : total25;
    hipLaunchKernelGGL(prep_kernel, dim3((tmax + 255) / 256), dim3(256), 0, stream,
                       seg, row_ptr, hidden, hb, n, P, total25);
    hipLaunchKernelGGL(gat_agg_kernel, dim3((n + 3) / 4), dim3(256), 0, stream,
                       hidden, W, nbr, row_ptr, hb, out, n, P);
}